// Round 16
// baseline (91.754 us; speedup 1.0000x reference)
//
#include <hip/hip_runtime.h>
#include <math.h>

#define EPSV 1e-6f
#define MAX_NORM (1.0f - 1e-3f)

typedef __attribute__((ext_vector_type(8))) short short8;   // 8 bf16 = 4 VGPRs
typedef __attribute__((ext_vector_type(4))) float f32x4;    // MFMA acc

// f32 -> bf16 (round-to-nearest-even), returns raw 16-bit pattern
__device__ inline ushort f32_to_bf16(float f) {
    union { float f; uint32_t u; } cv;
    cv.f = f;
    uint32_t u = cv.u;
    u += 0x7FFFu + ((u >> 16) & 1u);
    return (ushort)(u >> 16);
}

// async global -> LDS, 16 bytes per lane (dest = uniform base + lane*16)
__device__ inline void glds16(const ushort* gsrc, ushort* ldsdst) {
    auto* g = (const __attribute__((address_space(1))) uint32_t*)gsrc;
    auto* l = (__attribute__((address_space(3))) uint32_t*)ldsdst;
    __builtin_amdgcn_global_load_lds(g, l, 16, 0, 0);
}

// inline-asm ds_read_b128: opaque to compiler alias analysis (no auto vmcnt)
__device__ inline short8 ds_read128(const ushort* p) {
    auto* l3 = (const __attribute__((address_space(3))) ushort*)p;
    const uint32_t addr = (uint32_t)(uintptr_t)l3;
    short8 v;
    asm volatile("ds_read_b128 %0, %1" : "=&v"(v) : "v"(addr));
    return v;
}

// ---------------------------------------------------------------------------
// Kernel 1: expmap0 + clip for embeddings. One wave (64 lanes) per row, D=512.
// ---------------------------------------------------------------------------
__global__ void rows_emb_kernel(const float* __restrict__ emb,
                                const float* __restrict__ logc,
                                float* __restrict__ xh,
                                ushort* __restrict__ xbf,
                                float* __restrict__ x2raw,
                                float* __restrict__ dxv) {
    const int D = 512;
    const int row = blockIdx.x;
    const int lane = threadIdx.x;   // 0..63

    const float4* r4 = (const float4*)(emb + (size_t)row * D);
    float4 a = r4[2 * lane];
    float4 b = r4[2 * lane + 1];

    float ss = a.x * a.x + a.y * a.y + a.z * a.z + a.w * a.w
             + b.x * b.x + b.y * b.y + b.z * b.z + b.w * b.w;
#pragma unroll
    for (int off = 32; off > 0; off >>= 1) ss += __shfl_xor(ss, off, 64);

    const float c  = expf(logc[0]);
    const float sc = sqrtf(c);

    const float tn    = sqrtf(ss);
    const float vn    = fmaxf(tn, EPSV);
    const float coeff = tanhf(sc * vn) / (sc * vn);
    const float pre   = coeff * tn;
    const float fac   = fminf(MAX_NORM / fmaxf(pre, EPSV), 1.0f);
    const float scale = coeff * fac;

    float4 oa, ob;
    oa.x = a.x * scale; oa.y = a.y * scale; oa.z = a.z * scale; oa.w = a.w * scale;
    ob.x = b.x * scale; ob.y = b.y * scale; ob.z = b.z * scale; ob.w = b.w * scale;

    float4* o4 = (float4*)(xh + (size_t)row * D);
    o4[2 * lane]     = oa;
    o4[2 * lane + 1] = ob;

    union { ushort u[8]; uint4 v; } pk;
    pk.u[0] = f32_to_bf16(oa.x); pk.u[1] = f32_to_bf16(oa.y);
    pk.u[2] = f32_to_bf16(oa.z); pk.u[3] = f32_to_bf16(oa.w);
    pk.u[4] = f32_to_bf16(ob.x); pk.u[5] = f32_to_bf16(ob.y);
    pk.u[6] = f32_to_bf16(ob.z); pk.u[7] = f32_to_bf16(ob.w);
    ((uint4*)(xbf + (size_t)row * D))[lane] = pk.v;

    if (lane == 0) {
        const float sq = scale * scale * ss;
        x2raw[row] = sq;
        dxv[row]   = 1.0f - c * fminf(sq, MAX_NORM * MAX_NORM);
    }
}

// ---------------------------------------------------------------------------
// Kernel 2: clip-only for centroids. One wave per row, D=512.
// ---------------------------------------------------------------------------
__global__ void rows_cen_kernel(const float* __restrict__ cen,
                                const float* __restrict__ logc,
                                float* __restrict__ ch,
                                ushort* __restrict__ cbf,
                                float* __restrict__ y2raw,
                                float* __restrict__ dyv) {
    const int D = 512;
    const int row = blockIdx.x;
    const int lane = threadIdx.x;

    const float4* r4 = (const float4*)(cen + (size_t)row * D);
    float4 a = r4[2 * lane];
    float4 b = r4[2 * lane + 1];

    float ss = a.x * a.x + a.y * a.y + a.z * a.z + a.w * a.w
             + b.x * b.x + b.y * b.y + b.z * b.z + b.w * b.w;
#pragma unroll
    for (int off = 32; off > 0; off >>= 1) ss += __shfl_xor(ss, off, 64);

    const float c = expf(logc[0]);

    const float tn    = sqrtf(ss);
    const float scale = fminf(MAX_NORM / fmaxf(tn, EPSV), 1.0f);

    float4 oa, ob;
    oa.x = a.x * scale; oa.y = a.y * scale; oa.z = a.z * scale; oa.w = a.w * scale;
    ob.x = b.x * scale; ob.y = b.y * scale; ob.z = b.z * scale; ob.w = b.w * scale;

    float4* o4 = (float4*)(ch + (size_t)row * D);
    o4[2 * lane]     = oa;
    o4[2 * lane + 1] = ob;

    union { ushort u[8]; uint4 v; } pk;
    pk.u[0] = f32_to_bf16(oa.x); pk.u[1] = f32_to_bf16(oa.y);
    pk.u[2] = f32_to_bf16(oa.z); pk.u[3] = f32_to_bf16(oa.w);
    pk.u[4] = f32_to_bf16(ob.x); pk.u[5] = f32_to_bf16(ob.y);
    pk.u[6] = f32_to_bf16(ob.z); pk.u[7] = f32_to_bf16(ob.w);
    ((uint4*)(cbf + (size_t)row * D))[lane] = pk.v;

    if (lane == 0) {
        const float sq = scale * scale * ss;
        y2raw[row] = sq;
        dyv[row]   = 1.0f - c * fminf(sq, MAX_NORM * MAX_NORM);
    }
}

// ---------------------------------------------------------------------------
// Kernel 3: bf16 MFMA GEMM + Poincare epilogue.  BKT=64 DBUF, 4-PHASE.
// 256x256 tile, 8 waves (2Mx4N, each 128x64). NT=8 K-tiles. Per tile:
// vmcnt(0) [loads had a full ~2.5k-cy compute phase to land -> free] +
// ONE s_barrier, then 4 phases: {2 stage calls (tile t+1) || 4 next-phase
// A-reads -> lgkmcnt(4) -> 16 MFMA}. Fragment-order LDS (zero-conflict
// ds_read); all ds_read dests written once per tile (no WAR reuse).
// Runtime loop (R13-proven ordering shape). Epilogue: per-wave LDS
// transpose + float4-coalesced stores.
// ---------------------------------------------------------------------------
#define BM 256
#define BN 256
#define BKT 64
#define EPST 68   // epilogue LDS row stride in floats
#define KDIM 512
#define NT 8
#define NCOLS 4096

__global__ __launch_bounds__(512, 2)
void gemm_epi_kernel(const ushort* __restrict__ Abf,   // M x K bf16
                     const ushort* __restrict__ Bbf,   // N x K bf16
                     const float* __restrict__ x2raw,
                     const float* __restrict__ dxv,
                     const float* __restrict__ y2raw,
                     const float* __restrict__ dyv,
                     const float* __restrict__ logc,
                     float* __restrict__ out) {        // M x N
    // 128 KB dbuf: ring[p] = [A 16384 us | B 16384 us]. Unit (rg,kk) at
    // (rg*2+kk)*512 us: 16 rows x 32 k in exact MFMA fragment order
    // (lane l -> row l&15, k kk*32 + (l>>4)*8).
    __shared__ __align__(16) ushort ring[2][32768];

    const int tid  = threadIdx.x;
    const int lane = tid & 63;
    const int wid  = tid >> 6;     // 0..7
    const int wm   = wid >> 2;     // 0..1  (128-row half)
    const int wn   = wid & 3;      // 0..3  (64-col quarter)

    const int bm = blockIdx.y;
    const int bn = blockIdx.x;

    const ushort* Ab = Abf + (size_t)bm * BM * KDIM;
    const ushort* Bb = Bbf + (size_t)bn * BN * KDIM;

    f32x4 acc[8][4];
#pragma unroll
    for (int m = 0; m < 8; m++)
#pragma unroll
        for (int n = 0; n < 4; n++) acc[m][n] = (f32x4){0.f, 0.f, 0.f, 0.f};

    // Per-lane fragment-order source offset (kk=0 half of a unit).
    const size_t fragoff = (size_t)(lane & 15) * KDIM + ((lane >> 4) * 8);

    // Staging global bases (wave w stages A/B rowgroups 2w, 2w+1).
    const ushort* gA0 = Ab + (size_t)(2 * wid * 16) * KDIM + fragoff;
    const ushort* gA1 = gA0 + 16 * KDIM;
    const ushort* gB0 = Bb + (size_t)(2 * wid * 16) * KDIM + fragoff;
    const ushort* gB1 = gB0 + 16 * KDIM;

    // Staging LDS dests (wave-uniform): units 4w..4w+3 -> offset 4w*512.
    ushort* lA = &ring[0][0]     + wid * 2048;
    ushort* lB = &ring[0][16384] + wid * 2048;

    // Compute-read bases: af[m][kk] at wm*8192 + m*1024 + kk*512 (+lane*8);
    // bf[n][kk] at 16384 + wn*4096 + n*1024 + kk*512.
    const ushort* rdA = &ring[0][0]     + wm * 8192 + lane * 8;
    const ushort* rdB = &ring[0][16384] + wn * 4096 + lane * 8;

    // Prologue: stage tile 0 into buf 0 (8 calls/wave).
    glds16(gA0,      lA);        glds16(gA0 + 32, lA + 512);
    glds16(gA1,      lA + 1024); glds16(gA1 + 32, lA + 1536);
    glds16(gB0,      lB);        glds16(gB0 + 32, lB + 512);
    glds16(gB1,      lB + 1024); glds16(gB1 + 32, lB + 1536);

    for (int t = 0; t < NT; ++t) {
        // Tile t's 8 loads are the only outstanding VMEM -> vmcnt(0) is
        // exact; they had tile t-1's full compute to land.
        asm volatile("s_waitcnt vmcnt(0)" ::: "memory");
        __builtin_amdgcn_s_barrier();       // publish buf; t-1 reads done
        __builtin_amdgcn_sched_barrier(0);  // nothing crosses the seam

        const int p32 = (t & 1) * 32768;
        const ushort* rA = rdA + p32;
        const ushort* rB = rdB + p32;

        const bool st = (t + 1 < NT);
        const int koff = (t + 1) * BKT;               // staging k offset
        const int spd  = ((t + 1) & 1) * 32768;       // staging buf offset
        const ushort* sA0 = gA0 + koff;
        const ushort* sA1 = gA1 + koff;
        const ushort* sB0 = gB0 + koff;
        const ushort* sB1 = gB1 + koff;

        short8 bf[8], af[16];
        // Tile-top reads: all 8 B units + phase-0's 4 A units.
#pragma unroll
        for (int n = 0; n < 4; n++) {
            bf[2 * n]     = ds_read128(rB + n * 1024);
            bf[2 * n + 1] = ds_read128(rB + n * 1024 + 512);
        }
        af[0] = ds_read128(rA);
        af[1] = ds_read128(rA + 512);
        af[2] = ds_read128(rA + 1024);
        af[3] = ds_read128(rA + 1536);

#pragma unroll
        for (int q = 0; q < 4; ++q) {
            // ---- stage piece q for tile t+1 (2 calls) ----
            if (st) {
                if (q == 0) { glds16(sA0, lA + spd);        glds16(sA0 + 32, lA + spd + 512); }
                if (q == 1) { glds16(sA1, lA + spd + 1024); glds16(sA1 + 32, lA + spd + 1536); }
                if (q == 2) { glds16(sB0, lB + spd);        glds16(sB0 + 32, lB + spd + 512); }
                if (q == 3) { glds16(sB1, lB + spd + 1024); glds16(sB1 + 32, lB + spd + 1536); }
            }
            // ---- issue next phase's 4 A reads, wait for current 4 ----
            if (q < 3) {
                af[4 * q + 4] = ds_read128(rA + (2 * q + 2) * 1024);
                af[4 * q + 5] = ds_read128(rA + (2 * q + 2) * 1024 + 512);
                af[4 * q + 6] = ds_read128(rA + (2 * q + 3) * 1024);
                af[4 * q + 7] = ds_read128(rA + (2 * q + 3) * 1024 + 512);
                asm volatile("s_waitcnt lgkmcnt(4)" ::: "memory");
            } else {
                asm volatile("s_waitcnt lgkmcnt(0)" ::: "memory");
            }
            __builtin_amdgcn_sched_barrier(0);     // rule #18
            __builtin_amdgcn_s_setprio(1);
#pragma unroll
            for (int kk = 0; kk < 2; kk++)
#pragma unroll
                for (int n = 0; n < 4; n++) {
                    acc[2 * q][n] = __builtin_amdgcn_mfma_f32_16x16x32_bf16(
                        af[4 * q + kk], bf[2 * n + kk], acc[2 * q][n], 0, 0, 0);
                    acc[2 * q + 1][n] = __builtin_amdgcn_mfma_f32_16x16x32_bf16(
                        af[4 * q + 2 + kk], bf[2 * n + kk], acc[2 * q + 1][n], 0, 0, 0);
                }
            __builtin_amdgcn_s_setprio(0);
        }
    }

    __syncthreads();   // staging LDS -> epilogue reuse safety

    // ---------------- Epilogue: LDS transpose + coalesced stores ------------
    const float c   = expf(logc[0]);
    const float rsc = 1.0f / sqrtf(c);
    const int l16 = lane & 15;
    const int lg  = lane >> 4;

    float* ep = (float*)((char*)&ring[0][0] + (size_t)wid * 4352); // [16][EPST]
    const int gr_base = bm * BM + wm * 128;
    const int gc_base = bn * BN + wn * 64;

#pragma unroll
    for (int m = 0; m < 8; m++) {
        // scatter this m-frag (16 rows x 64 cols) into the private region
#pragma unroll
        for (int n = 0; n < 4; n++)
#pragma unroll
            for (int r = 0; r < 4; r++)
                ep[(lg * 4 + r) * EPST + n * 16 + l16] = acc[m][n][r];
        asm volatile("s_waitcnt lgkmcnt(0)" ::: "memory");

        // read back row-major: 4 iters x (4 rows x 16 float4 chunks)
#pragma unroll
        for (int it = 0; it < 4; it++) {
            const int row = it * 4 + lg;                  // 0..15
            const int gr  = gr_base + m * 16 + row;
            const int gc  = gc_base + l16 * 4;
            float4 xy4 = *(const float4*)&ep[row * EPST + l16 * 4];
            const float rx  = x2raw[gr];
            const float dxr = dxv[gr];
            const float4 ry4 = *(const float4*)&y2raw[gc];
            const float4 dy4 = *(const float4*)&dyv[gc];
            float4 o;
            {
                const float rden = __builtin_amdgcn_rcpf(fmaxf(dxr * dy4.x, EPSV));
                float t = fmaxf(2.0f * c * (rx + ry4.x - 2.0f * xy4.x) * rden, EPSV);
                o.x = __logf(1.0f + t + __builtin_amdgcn_sqrtf(t * (t + 2.0f))) * rsc;
            }
            {
                const float rden = __builtin_amdgcn_rcpf(fmaxf(dxr * dy4.y, EPSV));
                float t = fmaxf(2.0f * c * (rx + ry4.y - 2.0f * xy4.y) * rden, EPSV);
                o.y = __logf(1.0f + t + __builtin_amdgcn_sqrtf(t * (t + 2.0f))) * rsc;
            }
            {
                const float rden = __builtin_amdgcn_rcpf(fmaxf(dxr * dy4.z, EPSV));
                float t = fmaxf(2.0f * c * (rx + ry4.z - 2.0f * xy4.z) * rden, EPSV);
                o.z = __logf(1.0f + t + __builtin_amdgcn_sqrtf(t * (t + 2.0f))) * rsc;
            }
            {
                const float rden = __builtin_amdgcn_rcpf(fmaxf(dxr * dy4.w, EPSV));
                float t = fmaxf(2.0f * c * (rx + ry4.w - 2.0f * xy4.w) * rden, EPSV);
                o.w = __logf(1.0f + t + __builtin_amdgcn_sqrtf(t * (t + 2.0f))) * rsc;
            }
            *(float4*)&out[(size_t)gr * NCOLS + gc] = o;
        }
        asm volatile("s_waitcnt lgkmcnt(0)" ::: "memory");
    }
}

// ---------------------------------------------------------------------------
extern "C" void kernel_launch(void* const* d_in, const int* in_sizes, int n_in,
                              void* d_out, int out_size, void* d_ws, size_t ws_size,
                              hipStream_t stream) {
    const float* emb  = (const float*)d_in[0];   // (B, D) f32
    const float* logc = (const float*)d_in[1];   // scalar f32
    const float* cen  = (const float*)d_in[2];   // (C, D) f32

    const int D = 512;
    const int B = in_sizes[0] / D;   // 8192
    const int C = in_sizes[2] / D;   // 4096

    float* out   = (float*)d_out;
    float* dists = out;                          // B*C
    float* xh    = out + (size_t)B * C;          // B*D
    float* ch    = xh + (size_t)B * D;           // C*D

    char* ws = (char*)d_ws;
    size_t off = 0;
    auto alloc = [&](size_t bytes) -> char* {
        char* p = ws + off;
        off += (bytes + 255) & ~(size_t)255;
        return p;
    };
    ushort* xbf   = (ushort*)alloc((size_t)B * D * sizeof(ushort));
    ushort* cbf   = (ushort*)alloc((size_t)C * D * sizeof(ushort));
    float*  x2raw = (float*)alloc((size_t)B * sizeof(float));
    float*  dxv   = (float*)alloc((size_t)B * sizeof(float));
    float*  y2raw = (float*)alloc((size_t)C * sizeof(float));
    float*  dyv   = (float*)alloc((size_t)C * sizeof(float));

    rows_emb_kernel<<<B, 64, 0, stream>>>(emb, logc, xh, xbf, x2raw, dxv);
    rows_cen_kernel<<<C, 64, 0, stream>>>(cen, logc, ch, cbf, y2raw, dyv);

    dim3 grid(C / BN, B / BM);   // (16, 32)
    gemm_epi_kernel<<<grid, 512, 0, stream>>>(xbf, cbf, x2raw, dxv, y2raw, dyv,
                                              logc, dists);
}

// Round 18
// 85.670 us; speedup vs baseline: 1.0710x; 1.0710x over previous
//
#include <hip/hip_runtime.h>
#include <math.h>

#define EPSV 1e-6f
#define MAX_NORM (1.0f - 1e-3f)

typedef __attribute__((ext_vector_type(8))) short short8;   // 8 bf16 = 4 VGPRs
typedef __attribute__((ext_vector_type(4))) float f32x4;    // MFMA acc

// f32 -> bf16 (round-to-nearest-even), returns raw 16-bit pattern
__device__ inline ushort f32_to_bf16(float f) {
    union { float f; uint32_t u; } cv;
    cv.f = f;
    uint32_t u = cv.u;
    u += 0x7FFFu + ((u >> 16) & 1u);
    return (ushort)(u >> 16);
}

// async global -> LDS, 16 bytes per lane (dest = uniform base + lane*16)
__device__ inline void glds16(const ushort* gsrc, ushort* ldsdst) {
    auto* g = (const __attribute__((address_space(1))) uint32_t*)gsrc;
    auto* l = (__attribute__((address_space(3))) uint32_t*)ldsdst;
    __builtin_amdgcn_global_load_lds(g, l, 16, 0, 0);
}

// inline-asm ds_read_b128: opaque to compiler alias analysis (no auto vmcnt)
__device__ inline short8 ds_read128(const ushort* p) {
    auto* l3 = (const __attribute__((address_space(3))) ushort*)p;
    const uint32_t addr = (uint32_t)(uintptr_t)l3;
    short8 v;
    asm volatile("ds_read_b128 %0, %1" : "=&v"(v) : "v"(addr));
    return v;
}

// ---------------------------------------------------------------------------
// Kernel 1: expmap0 + clip for embeddings. One wave (64 lanes) per row, D=512.
// ---------------------------------------------------------------------------
__global__ void rows_emb_kernel(const float* __restrict__ emb,
                                const float* __restrict__ logc,
                                float* __restrict__ xh,
                                ushort* __restrict__ xbf,
                                float* __restrict__ x2raw,
                                float* __restrict__ dxv) {
    const int D = 512;
    const int row = blockIdx.x;
    const int lane = threadIdx.x;   // 0..63

    const float4* r4 = (const float4*)(emb + (size_t)row * D);
    float4 a = r4[2 * lane];
    float4 b = r4[2 * lane + 1];

    float ss = a.x * a.x + a.y * a.y + a.z * a.z + a.w * a.w
             + b.x * b.x + b.y * b.y + b.z * b.z + b.w * b.w;
#pragma unroll
    for (int off = 32; off > 0; off >>= 1) ss += __shfl_xor(ss, off, 64);

    const float c  = expf(logc[0]);
    const float sc = sqrtf(c);

    const float tn    = sqrtf(ss);
    const float vn    = fmaxf(tn, EPSV);
    const float coeff = tanhf(sc * vn) / (sc * vn);
    const float pre   = coeff * tn;
    const float fac   = fminf(MAX_NORM / fmaxf(pre, EPSV), 1.0f);
    const float scale = coeff * fac;

    float4 oa, ob;
    oa.x = a.x * scale; oa.y = a.y * scale; oa.z = a.z * scale; oa.w = a.w * scale;
    ob.x = b.x * scale; ob.y = b.y * scale; ob.z = b.z * scale; ob.w = b.w * scale;

    float4* o4 = (float4*)(xh + (size_t)row * D);
    o4[2 * lane]     = oa;
    o4[2 * lane + 1] = ob;

    union { ushort u[8]; uint4 v; } pk;
    pk.u[0] = f32_to_bf16(oa.x); pk.u[1] = f32_to_bf16(oa.y);
    pk.u[2] = f32_to_bf16(oa.z); pk.u[3] = f32_to_bf16(oa.w);
    pk.u[4] = f32_to_bf16(ob.x); pk.u[5] = f32_to_bf16(ob.y);
    pk.u[6] = f32_to_bf16(ob.z); pk.u[7] = f32_to_bf16(ob.w);
    ((uint4*)(xbf + (size_t)row * D))[lane] = pk.v;

    if (lane == 0) {
        const float sq = scale * scale * ss;
        x2raw[row] = sq;
        dxv[row]   = 1.0f - c * fminf(sq, MAX_NORM * MAX_NORM);
    }
}

// ---------------------------------------------------------------------------
// Kernel 2: clip-only for centroids. One wave per row, D=512.
// ---------------------------------------------------------------------------
__global__ void rows_cen_kernel(const float* __restrict__ cen,
                                const float* __restrict__ logc,
                                float* __restrict__ ch,
                                ushort* __restrict__ cbf,
                                float* __restrict__ y2raw,
                                float* __restrict__ dyv) {
    const int D = 512;
    const int row = blockIdx.x;
    const int lane = threadIdx.x;

    const float4* r4 = (const float4*)(cen + (size_t)row * D);
    float4 a = r4[2 * lane];
    float4 b = r4[2 * lane + 1];

    float ss = a.x * a.x + a.y * a.y + a.z * a.z + a.w * a.w
             + b.x * b.x + b.y * b.y + b.z * b.z + b.w * b.w;
#pragma unroll
    for (int off = 32; off > 0; off >>= 1) ss += __shfl_xor(ss, off, 64);

    const float c = expf(logc[0]);

    const float tn    = sqrtf(ss);
    const float scale = fminf(MAX_NORM / fmaxf(tn, EPSV), 1.0f);

    float4 oa, ob;
    oa.x = a.x * scale; oa.y = a.y * scale; oa.z = a.z * scale; oa.w = a.w * scale;
    ob.x = b.x * scale; ob.y = b.y * scale; ob.z = b.z * scale; ob.w = b.w * scale;

    float4* o4 = (float4*)(ch + (size_t)row * D);
    o4[2 * lane]     = oa;
    o4[2 * lane + 1] = ob;

    union { ushort u[8]; uint4 v; } pk;
    pk.u[0] = f32_to_bf16(oa.x); pk.u[1] = f32_to_bf16(oa.y);
    pk.u[2] = f32_to_bf16(oa.z); pk.u[3] = f32_to_bf16(oa.w);
    pk.u[4] = f32_to_bf16(ob.x); pk.u[5] = f32_to_bf16(ob.y);
    pk.u[6] = f32_to_bf16(ob.z); pk.u[7] = f32_to_bf16(ob.w);
    ((uint4*)(cbf + (size_t)row * D))[lane] = pk.v;

    if (lane == 0) {
        const float sq = scale * scale * ss;
        y2raw[row] = sq;
        dyv[row]   = 1.0f - c * fminf(sq, MAX_NORM * MAX_NORM);
    }
}

// ---------------------------------------------------------------------------
// Kernel 3: bf16 MFMA GEMM + Poincare epilogue.  m201-TEMPLATE, BKT=32,
// RING-OF-3 (consistent geometry), COUNTED SEAM vmcnt(4).
// 256x256 tile, NT=16, 8 waves (2Mx4N, each 128x64).
// Ring buf r at r*16384 us (32KB): [A 8192 us | B 8192 us]; unit u (16 rows
// x 32 k) at u*512 us, exact MFMA fragment order (lane l -> row l&15,
// k (l>>4)*8). Wave w stages A units 2w,2w+1 + B units 2w,2w+1 (4 calls).
// Per tile: seam {vmcnt(4); s_barrier} (tile t+1's 4 loads stay in flight
// -- never drains to 0 mid-loop), then 4 phases, each the m201 template:
// {issue ds_reads; 1 stage call (t+2); s_barrier; lgkmcnt(0);
// sched_barrier(0); setprio(1); 8 MFMA; setprio(0); s_barrier}.
// Epilogue: per-wave LDS transpose + float4-coalesced stores.
// ---------------------------------------------------------------------------
#define BM 256
#define BN 256
#define BKT 32
#define EPST 68
#define KDIM 512
#define NT 16
#define NCOLS 4096

__global__ __launch_bounds__(512, 1)
void gemm_epi_kernel(const ushort* __restrict__ Abf,   // M x K bf16
                     const ushort* __restrict__ Bbf,   // N x K bf16
                     const float* __restrict__ x2raw,
                     const float* __restrict__ dxv,
                     const float* __restrict__ y2raw,
                     const float* __restrict__ dyv,
                     const float* __restrict__ logc,
                     float* __restrict__ out) {        // M x N
    __shared__ __align__(16) ushort ring[3 * 16384];   // 96 KB

    const int tid  = threadIdx.x;
    const int lane = tid & 63;
    const int wid  = tid >> 6;     // 0..7
    const int wm   = wid >> 2;     // 0..1
    const int wn   = wid & 3;      // 0..3

    const int bm = blockIdx.y;
    const int bn = blockIdx.x;

    const ushort* Ab = Abf + (size_t)bm * BM * KDIM;
    const ushort* Bb = Bbf + (size_t)bn * BN * KDIM;

    f32x4 acc[8][4];
#pragma unroll
    for (int m = 0; m < 8; m++)
#pragma unroll
        for (int n = 0; n < 4; n++) acc[m][n] = (f32x4){0.f, 0.f, 0.f, 0.f};

    const size_t fragoff = (size_t)(lane & 15) * KDIM + ((lane >> 4) * 8);

    // Staging global bases: wave w covers A rows 32w..32w+31 (units 2w,2w+1).
    const ushort* gA0 = Ab + (size_t)(2 * wid) * 16 * KDIM + fragoff;
    const ushort* gA1 = gA0 + 16 * KDIM;
    const ushort* gB0 = Bb + (size_t)(2 * wid) * 16 * KDIM + fragoff;
    const ushort* gB1 = gB0 + 16 * KDIM;

    // Staging LDS dests (wave-uniform), buf 0; add r*16384 per buffer.
    ushort* lA = &ring[0]    + wid * 1024;    // unit 2w; 2w+1 at +512
    ushort* lB = &ring[8192] + wid * 1024;

    // Compute-read bases: A units 8wm..8wm+7; B units 4wn..4wn+3.
    const ushort* rdA = &ring[0]    + wm * 4096 + lane * 8;
    const ushort* rdB = &ring[8192] + wn * 2048 + lane * 8;

    // Full-tile stage: 4 calls for tile t into buf r.
    auto stage_tile = [&](int r, int t) {
        const int ko = t * BKT;
        glds16(gA0 + ko, lA + r * 16384);
        glds16(gA1 + ko, lA + r * 16384 + 512);
        glds16(gB0 + ko, lB + r * 16384);
        glds16(gB1 + ko, lB + r * 16384 + 512);
    };

    // Prologue: stage tiles 0 and 1 (8 outstanding/wave).
    stage_tile(0, 0);
    stage_tile(1, 1);

    for (int t = 0; t < NT; ++t) {
        // ---- seam: counted drain; t+1's 4 loads stay in flight ----
        if (t < NT - 1) asm volatile("s_waitcnt vmcnt(4)" ::: "memory");
        else            asm volatile("s_waitcnt vmcnt(0)" ::: "memory");
        __builtin_amdgcn_s_barrier();

        const int r16 = (t % 3) * 16384;
        const ushort* rA = rdA + r16;
        const ushort* rB = rdB + r16;

        const bool st  = (t + 2 < NT);
        const int  sr  = ((t + 2) % 3) * 16384;
        const int  sko = (t + 2) * BKT;

        short8 bf[4];   // B units, persistent across the tile's 4 phases

#pragma unroll
        for (int q = 0; q < 4; ++q) {
            // ---- issue: this phase's ds_reads ----
            short8 a0, a1;
            if (q == 0) {
#pragma unroll
                for (int n = 0; n < 4; n++)
                    bf[n] = ds_read128(rB + n * 512);
            }
            a0 = ds_read128(rA + (2 * q) * 512);
            a1 = ds_read128(rA + (2 * q + 1) * 512);

            // ---- issue: 1 staging call for tile t+2 ----
            if (st) {
                if (q == 0) glds16(gA0 + sko, lA + sr);
                if (q == 1) glds16(gA1 + sko, lA + sr + 512);
                if (q == 2) glds16(gB0 + sko, lB + sr);
                if (q == 3) glds16(gB1 + sko, lB + sr + 512);
            }

            __builtin_amdgcn_s_barrier();
            asm volatile("s_waitcnt lgkmcnt(0)" ::: "memory");
            __builtin_amdgcn_sched_barrier(0);   // rule #18
            __builtin_amdgcn_s_setprio(1);
#pragma unroll
            for (int n = 0; n < 4; n++) {
                acc[2 * q][n]     = __builtin_amdgcn_mfma_f32_16x16x32_bf16(
                    a0, bf[n], acc[2 * q][n], 0, 0, 0);
                acc[2 * q + 1][n] = __builtin_amdgcn_mfma_f32_16x16x32_bf16(
                    a1, bf[n], acc[2 * q + 1][n], 0, 0, 0);
            }
            __builtin_amdgcn_sched_barrier(0);   // keep cluster inside prio
            __builtin_amdgcn_s_setprio(0);
            __builtin_amdgcn_s_barrier();
        }
    }

    __syncthreads();   // staging LDS -> epilogue reuse safety

    // ---------------- Epilogue: LDS transpose + coalesced stores ------------
    const float c   = expf(logc[0]);
    const float rsc = 1.0f / sqrtf(c);
    const int l16 = lane & 15;
    const int lg  = lane >> 4;

    float* ep = (float*)((char*)&ring[0] + (size_t)wid * 4352); // [16][EPST]
    const int gr_base = bm * BM + wm * 128;
    const int gc_base = bn * BN + wn * 64;

#pragma unroll
    for (int m = 0; m < 8; m++) {
#pragma unroll
        for (int n = 0; n < 4; n++)
#pragma unroll
            for (int r = 0; r < 4; r++)
                ep[(lg * 4 + r) * EPST + n * 16 + l16] = acc[m][n][r];
        asm volatile("s_waitcnt lgkmcnt(0)" ::: "memory");

#pragma unroll
        for (int it = 0; it < 4; it++) {
            const int row = it * 4 + lg;                  // 0..15
            const int gr  = gr_base + m * 16 + row;
            const int gc  = gc_base + l16 * 4;
            float4 xy4 = *(const float4*)&ep[row * EPST + l16 * 4];
            const float rx  = x2raw[gr];
            const float dxr = dxv[gr];
            const float4 ry4 = *(const float4*)&y2raw[gc];
            const float4 dy4 = *(const float4*)&dyv[gc];
            float4 o;
            {
                const float rden = __builtin_amdgcn_rcpf(fmaxf(dxr * dy4.x, EPSV));
                float t = fmaxf(2.0f * c * (rx + ry4.x - 2.0f * xy4.x) * rden, EPSV);
                o.x = __logf(1.0f + t + __builtin_amdgcn_sqrtf(t * (t + 2.0f))) * rsc;
            }
            {
                const float rden = __builtin_amdgcn_rcpf(fmaxf(dxr * dy4.y, EPSV));
                float t = fmaxf(2.0f * c * (rx + ry4.y - 2.0f * xy4.y) * rden, EPSV);
                o.y = __logf(1.0f + t + __builtin_amdgcn_sqrtf(t * (t + 2.0f))) * rsc;
            }
            {
                const float rden = __builtin_amdgcn_rcpf(fmaxf(dxr * dy4.z, EPSV));
                float t = fmaxf(2.0f * c * (rx + ry4.z - 2.0f * xy4.z) * rden, EPSV);
                o.z = __logf(1.0f + t + __builtin_amdgcn_sqrtf(t * (t + 2.0f))) * rsc;
            }
            {
                const float rden = __builtin_amdgcn_rcpf(fmaxf(dxr * dy4.w, EPSV));
                float t = fmaxf(2.0f * c * (rx + ry4.w - 2.0f * xy4.w) * rden, EPSV);
                o.w = __logf(1.0f + t + __builtin_amdgcn_sqrtf(t * (t + 2.0f))) * rsc;
            }
            *(float4*)&out[(size_t)gr * NCOLS + gc] = o;
        }
        asm volatile("s_waitcnt lgkmcnt(0)" ::: "memory");
    }
}

// ---------------------------------------------------------------------------
extern "C" void kernel_launch(void* const* d_in, const int* in_sizes, int n_in,
                              void* d_out, int out_size, void* d_ws, size_t ws_size,
                              hipStream_t stream) {
    const float* emb  = (const float*)d_in[0];   // (B, D) f32
    const float* logc = (const float*)d_in[1];   // scalar f32
    const float* cen  = (const float*)d_in[2];   // (C, D) f32

    const int D = 512;
    const int B = in_sizes[0] / D;   // 8192
    const int C = in_sizes[2] / D;   // 4096

    float* out   = (float*)d_out;
    float* dists = out;                          // B*C
    float* xh    = out + (size_t)B * C;          // B*D
    float* ch    = xh + (size_t)B * D;           // C*D

    char* ws = (char*)d_ws;
    size_t off = 0;
    auto alloc = [&](size_t bytes) -> char* {
        char* p = ws + off;
        off += (bytes + 255) & ~(size_t)255;
        return p;
    };
    ushort* xbf   = (ushort*)alloc((size_t)B * D * sizeof(ushort));
    ushort* cbf   = (ushort*)alloc((size_t)C * D * sizeof(ushort));
    float*  x2raw = (float*)alloc((size_t)B * sizeof(float));
    float*  dxv   = (float*)alloc((size_t)B * sizeof(float));
    float*  y2raw = (float*)alloc((size_t)C * sizeof(float));
    float*  dyv   = (float*)alloc((size_t)C * sizeof(float));

    rows_emb_kernel<<<B, 64, 0, stream>>>(emb, logc, xh, xbf, x2raw, dxv);
    rows_cen_kernel<<<C, 64, 0, stream>>>(cen, logc, ch, cbf, y2raw, dyv);

    dim3 grid(C / BN, B / BM);   // (16, 32)
    gemm_epi_kernel<<<grid, 512, 0, stream>>>(xbf, cbf, x2raw, dxv, y2raw, dyv,
                                              logc, dists);
}